// Round 1
// baseline (91.687 us; speedup 1.0000x reference)
//
#include <hip/hip_runtime.h>
#include <math.h>

#define B 8192
#define D 256
#define NCLS 512
#define ALPHA 0.1f

// ---------------------------------------------------------------------------
// Kernel 1: per-row inverse L2 norm. One wave (64 lanes) per row; each lane
// loads float4 (4 floats) -> 64*4 = 256 = D floats per row. Shfl-reduce.
// ---------------------------------------------------------------------------
__global__ __launch_bounds__(256) void k_norms(const float* __restrict__ y_pred,
                                               float* __restrict__ inv_norm) {
    const int wave = threadIdx.x >> 6;
    const int lane = threadIdx.x & 63;
    const int row  = blockIdx.x * 4 + wave;
    const float4* p = (const float4*)(y_pred + (size_t)row * D);
    float4 v = p[lane];
    float s = v.x * v.x + v.y * v.y + v.z * v.z + v.w * v.w;
#pragma unroll
    for (int off = 32; off > 0; off >>= 1) s += __shfl_down(s, off, 64);
    if (lane == 0) inv_norm[row] = (s > 0.0f) ? (1.0f / sqrtf(s)) : 0.0f;
}

// ---------------------------------------------------------------------------
// Kernel 2: one block per class. Scan labels, compact matching row indices
// into LDS, then thread d accumulates the class-sum vector component d.
// Contributions: t[d] += s_c[d]; S_pos += ||s_c||^2; n_pos += count^2.
// ---------------------------------------------------------------------------
__global__ __launch_bounds__(256) void k_class(const int* __restrict__ labels,
                                               const float* __restrict__ y_pred,
                                               const float* __restrict__ inv_norm,
                                               float* __restrict__ t,
                                               float* __restrict__ s_pos,
                                               float* __restrict__ n_pos) {
    __shared__ int list[B];     // worst case: every row in this class (32 KB)
    __shared__ int cnt;
    __shared__ float red[4];
    const int c   = blockIdx.x;
    const int tid = threadIdx.x;
    if (tid == 0) cnt = 0;
    __syncthreads();

    // Compact row indices with label == c (order irrelevant for a sum).
    for (int k = tid; k < B; k += 256) {
        if (labels[k] == c) {
            int idx = atomicAdd(&cnt, 1);
            list[idx] = k;
        }
    }
    __syncthreads();

    const int n = cnt;
    float acc = 0.0f;
    for (int j = 0; j < n; ++j) {
        const int i = list[j];
        acc += y_pred[(size_t)i * D + tid] * inv_norm[i];
    }

    // Global per-dim total (for S_all later).
    atomicAdd(&t[tid], acc);

    // Block-reduce acc^2 -> ||s_c||^2.
    float sq = acc * acc;
#pragma unroll
    for (int off = 32; off > 0; off >>= 1) sq += __shfl_down(sq, off, 64);
    if ((tid & 63) == 0) red[tid >> 6] = sq;
    __syncthreads();
    if (tid == 0) {
        float tot = red[0] + red[1] + red[2] + red[3];
        atomicAdd(s_pos, tot);
        atomicAdd(n_pos, (float)n * (float)n);
    }
}

// ---------------------------------------------------------------------------
// Kernel 3: S_all = ||t||^2; assemble the scalar loss.
// ---------------------------------------------------------------------------
__global__ __launch_bounds__(256) void k_final(const float* __restrict__ t,
                                               const float* __restrict__ s_pos,
                                               const float* __restrict__ n_pos,
                                               float* __restrict__ out) {
    __shared__ float red[4];
    const int tid = threadIdx.x;
    float v = t[tid];
    float sq = v * v;
#pragma unroll
    for (int off = 32; off > 0; off >>= 1) sq += __shfl_down(sq, off, 64);
    if ((tid & 63) == 0) red[tid >> 6] = sq;
    __syncthreads();
    if (tid == 0) {
        const float s_all = red[0] + red[1] + red[2] + red[3];
        const float sp  = *s_pos;
        const float np_ = *n_pos;
        const float nn  = (float)B * (float)B - np_;
        const float pd  = sp / np_;
        const float nd  = (s_all - sp) / nn;
        const float r   = pd - nd + ALPHA;
        *out = (r > 0.0f) ? r : 0.0f;
    }
}

// ---------------------------------------------------------------------------
// Workspace layout (bytes):
//   [0, 32768)        inv_norm   : B floats
//   [32768, 33792)    t          : D floats   (zeroed)
//   [33792, 33796)    S_pos      : 1 float    (zeroed)
//   [33796, 33800)    n_pos      : 1 float    (zeroed)
// ---------------------------------------------------------------------------
extern "C" void kernel_launch(void* const* d_in, const int* in_sizes, int n_in,
                              void* d_out, int out_size, void* d_ws, size_t ws_size,
                              hipStream_t stream) {
    const int*   y_true = (const int*)d_in[0];
    const float* y_pred = (const float*)d_in[1];
    float* out = (float*)d_out;

    char* ws = (char*)d_ws;
    float* inv_norm = (float*)(ws);
    float* t        = (float*)(ws + 32768);
    float* s_pos    = (float*)(ws + 33792);
    float* n_pos    = (float*)(ws + 33796);

    // Zero t + scalars (ws is re-poisoned to 0xAA before every launch).
    hipMemsetAsync(ws + 32768, 0, 1024 + 8, stream);

    k_norms<<<B / 4, 256, 0, stream>>>(y_pred, inv_norm);
    k_class<<<NCLS, 256, 0, stream>>>(y_true, y_pred, inv_norm, t, s_pos, n_pos);
    k_final<<<1, 256, 0, stream>>>(t, s_pos, n_pos, out);
}

// Round 2
// 80.386 us; speedup vs baseline: 1.1406x; 1.1406x over previous
//
#include <hip/hip_runtime.h>
#include <math.h>

#define B 8192
#define D 256
#define NCLS 512
#define ALPHA 0.1f

// ---------------------------------------------------------------------------
// Kernel A: one block (256 thr = 4 waves) per class.
//  1) vectorized (int4) cooperative scan of labels -> compacted LDS row list
//  2) wave w handles rows j == w (mod 4): lane loads float4 of the row
//     (64 lanes * 4 = 256 = D), in-wave shfl_xor butterfly gives sumsq to all
//     lanes (no block sync), acc += v * inv_norm
//  3) combine 4 wave partials via LDS, write s_c[256] + cnt_c unconditionally
//     (no zero-init of ws needed, no global atomics)
// ---------------------------------------------------------------------------
__global__ __launch_bounds__(256) void k_class(const int* __restrict__ labels,
                                               const float* __restrict__ y_pred,
                                               float* __restrict__ s,     // [NCLS][D]
                                               int* __restrict__ cnt_out) // [NCLS]
{
    __shared__ int   list[B];      // 32 KB worst case
    __shared__ int   cnt;
    __shared__ float accs[4][D];   // 4 KB wave partials

    const int c    = blockIdx.x;
    const int tid  = threadIdx.x;
    const int wave = tid >> 6;
    const int lane = tid & 63;

    if (tid == 0) cnt = 0;
    __syncthreads();

    // ---- label scan, int4-vectorized (8 iterations) ----
    const int4* l4 = (const int4*)labels;
    for (int k = tid; k < B / 4; k += 256) {
        int4 v = l4[k];
        if (v.x == c) list[atomicAdd(&cnt, 1)] = 4 * k + 0;
        if (v.y == c) list[atomicAdd(&cnt, 1)] = 4 * k + 1;
        if (v.z == c) list[atomicAdd(&cnt, 1)] = 4 * k + 2;
        if (v.w == c) list[atomicAdd(&cnt, 1)] = 4 * k + 3;
    }
    __syncthreads();
    const int n = cnt;

    // ---- per-wave: norm + accumulate (no block syncs inside) ----
    float4 acc = make_float4(0.f, 0.f, 0.f, 0.f);
    for (int j = wave; j < n; j += 4) {
        const int i = list[j];
        const float4* row = (const float4*)(y_pred + (size_t)i * D);
        float4 v = row[lane];
        float sq = v.x * v.x + v.y * v.y + v.z * v.z + v.w * v.w;
#pragma unroll
        for (int off = 32; off; off >>= 1) sq += __shfl_xor(sq, off, 64);
        const float inv = (sq > 0.f) ? (1.0f / sqrtf(sq)) : 0.f;
        acc.x += v.x * inv; acc.y += v.y * inv;
        acc.z += v.z * inv; acc.w += v.w * inv;
    }
    ((float4*)accs[wave])[lane] = acc;
    __syncthreads();

    // ---- combine wave partials; thread tid owns dim d = tid ----
    const float sum = accs[0][tid] + accs[1][tid] + accs[2][tid] + accs[3][tid];
    s[(size_t)c * D + tid] = sum;
    if (tid == 0) cnt_out[c] = n;
}

// ---------------------------------------------------------------------------
// Kernel B: single block, 1024 threads. group g = tid>>8 strides classes.
//   S_pos = sum_c ||s_c||^2 = sum_d sum_c s_c[d]^2   (separable -> per-thread)
//   t_d   = sum_c s_c[d]  (LDS combine of 4 group partials), S_all = ||t||^2
//   n_pos = sum_c cnt_c^2
// ---------------------------------------------------------------------------
__global__ __launch_bounds__(1024) void k_final(const float* __restrict__ s,
                                                const int* __restrict__ cnt,
                                                float* __restrict__ out)
{
    __shared__ float tpart[4][D];
    __shared__ float redsq[16];
    __shared__ float redall[4];
    __shared__ float rednp[4];

    const int tid = threadIdx.x;
    const int g = tid >> 8;
    const int d = tid & 255;

    float tl = 0.f, sq = 0.f;
#pragma unroll 4
    for (int c = g; c < NCLS; c += 4) {
        const float v = s[(size_t)c * D + d];
        tl += v;
        sq += v * v;
    }
    tpart[g][d] = tl;
#pragma unroll
    for (int off = 32; off; off >>= 1) sq += __shfl_xor(sq, off, 64);
    if ((tid & 63) == 0) redsq[tid >> 6] = sq;
    __syncthreads();

    float sall = 0.f, np = 0.f;
    if (g == 0) {  // wave-uniform branch (4 whole waves)
        const float t_d = tpart[0][d] + tpart[1][d] + tpart[2][d] + tpart[3][d];
        sall = t_d * t_d;
        const float c0 = (float)cnt[d];
        const float c1 = (float)cnt[d + 256];
        np = c0 * c0 + c1 * c1;
#pragma unroll
        for (int off = 32; off; off >>= 1) {
            sall += __shfl_xor(sall, off, 64);
            np   += __shfl_xor(np,   off, 64);
        }
        if ((d & 63) == 0) { redall[d >> 6] = sall; rednp[d >> 6] = np; }
    }
    __syncthreads();

    if (tid == 0) {
        float s_pos = 0.f;
#pragma unroll
        for (int i = 0; i < 16; ++i) s_pos += redsq[i];
        const float s_all = redall[0] + redall[1] + redall[2] + redall[3];
        const float np_   = rednp[0] + rednp[1] + rednp[2] + rednp[3];
        const float nn    = (float)B * (float)B - np_;
        const float pd    = s_pos / np_;
        const float nd    = (s_all - s_pos) / nn;
        const float r     = pd - nd + ALPHA;
        *out = (r > 0.f) ? r : 0.f;
    }
}

// ---------------------------------------------------------------------------
// Workspace layout (no zero-init required — everything written before read):
//   [0, 512KB)           s   : NCLS*D floats
//   [512KB, 512KB+2KB)   cnt : NCLS ints
// ---------------------------------------------------------------------------
extern "C" void kernel_launch(void* const* d_in, const int* in_sizes, int n_in,
                              void* d_out, int out_size, void* d_ws, size_t ws_size,
                              hipStream_t stream) {
    const int*   y_true = (const int*)d_in[0];
    const float* y_pred = (const float*)d_in[1];
    float* out = (float*)d_out;

    char* ws = (char*)d_ws;
    float* s   = (float*)(ws);
    int*   cnt = (int*)(ws + (size_t)NCLS * D * sizeof(float));

    k_class<<<NCLS, 256, 0, stream>>>(y_true, y_pred, s, cnt);
    k_final<<<1, 1024, 0, stream>>>(s, cnt, out);
}